// Round 8
// baseline (92.741 us; speedup 1.0000x reference)
//
#include <hip/hip_runtime.h>

#define D 64
#define STR 72  // LDS row stride in bf16 elems (r4-verbatim)

typedef __attribute__((ext_vector_type(8))) short bf16x8;
typedef __attribute__((ext_vector_type(4))) float f32x4;
typedef __attribute__((ext_vector_type(4))) unsigned int u32x4;

static __device__ __forceinline__ unsigned short f2bf(float f) {
  unsigned u = __builtin_bit_cast(unsigned, f);
  u += 0x7fffu + ((u >> 16) & 1u);  // RNE
  return (unsigned short)(u >> 16);
}

// r4's exact wave-private LDS ordering macro (P write -> pf read, own region)
#define LDSWAIT() asm volatile("s_waitcnt lgkmcnt(0)" ::: "memory")

// One BLOCK per sequence; 4 waves split the query tiles (wave w -> tile w).
// H staged ONCE into shared LDS (9.2 KB) -> 8 blocks/CU, 4096 blocks total
// = 2x oversubscription -> backfill removes the L-imbalance tail.
// All __syncthreads precede any wave-divergent branch.
__global__ __launch_bounds__(256, 8)
void seq_attn_kernel(const float* __restrict__ h,
                     const int* __restrict__ sse,  // int32 (JAX x64 disabled)
                     float* __restrict__ out) {
  __shared__ unsigned short Hs[64 * STR];  // 9216 B: H tile, later reused for P

  const int tid = threadIdx.x;
  const int w = tid >> 6;
  const int lane = tid & 63;

  const int s = blockIdx.x;
  const int start = sse[2 * s];
  const int L = sse[2 * s + 1] - start;
  const int nt = (L + 15) >> 4;  // live 16-row tiles
  const int g = lane >> 4;
  const int c16 = lane & 15;

  const float* src = h + (size_t)start * D;

  // ---- stage H fp32->bf16 into shared Hs, 256 threads, zero-pad rows >= L ----
  // thread -> row = tid>>2, 64B chunk = (tid&3)*16; whole seq region contiguous.
  {
    const int r = tid >> 2;
    const int c0 = (tid & 3) * 16;
    const bool ok = (r < L);
    const float4 fz = make_float4(0.f, 0.f, 0.f, 0.f);
    const float* p0 = src + (size_t)r * D + c0;
    float4 v0 = ok ? *(const float4*)(p0 + 0) : fz;
    float4 v1 = ok ? *(const float4*)(p0 + 4) : fz;
    float4 v2 = ok ? *(const float4*)(p0 + 8) : fz;
    float4 v3 = ok ? *(const float4*)(p0 + 12) : fz;
    *(ushort4*)&Hs[r * STR + c0 + 0]  = make_ushort4(f2bf(v0.x), f2bf(v0.y), f2bf(v0.z), f2bf(v0.w));
    *(ushort4*)&Hs[r * STR + c0 + 4]  = make_ushort4(f2bf(v1.x), f2bf(v1.y), f2bf(v1.z), f2bf(v1.w));
    *(ushort4*)&Hs[r * STR + c0 + 8]  = make_ushort4(f2bf(v2.x), f2bf(v2.y), f2bf(v2.z), f2bf(v2.w));
    *(ushort4*)&Hs[r * STR + c0 + 12] = make_ushort4(f2bf(v3.x), f2bf(v3.y), f2bf(v3.z), f2bf(v3.w));
  }
  __syncthreads();

  // ---- fragment loads from shared Hs (r4-verbatim addressing; same for all waves) ----
  bf16x8 hf[4][2];
  #pragma unroll
  for (int t = 0; t < 4; ++t)
    #pragma unroll
    for (int kb = 0; kb < 2; ++kb)
      hf[t][kb] = *(const bf16x8*)&Hs[(t * 16 + c16) * STR + kb * 32 + g * 8];

  bf16x8 vf[4][2];
  #pragma unroll
  for (int t = 0; t < 4; ++t)
    #pragma unroll
    for (int kb = 0; kb < 2; ++kb) {
      u32x4 wv;
      #pragma unroll
      for (int dd = 0; dd < 4; ++dd) {
        const int k0 = kb * 32 + g * 8 + 2 * dd;
        const unsigned lo = Hs[k0 * STR + t * 16 + c16];
        const unsigned hi2 = Hs[(k0 + 1) * STR + t * 16 + c16];
        wv[dd] = lo | (hi2 << 16);
      }
      vf[t][kb] = __builtin_bit_cast(bf16x8, wv);
    }

  __syncthreads();  // all fragment reads done before P overwrites Hs

  // ---- wave w computes query tile w (r4 per-tile body verbatim, ti = w) ----
  const int ti = w;
  if (ti < nt) {
    unsigned short* P = Hs + ti * 16 * STR;  // wave-private 16-row region

    f32x4 acc[4];
    #pragma unroll
    for (int tj = 0; tj < 4; ++tj) {
      f32x4 z = {0.f, 0.f, 0.f, 0.f};
      acc[tj] = z;
    }
    #pragma unroll
    for (int tj = 0; tj < 4; ++tj)
      #pragma unroll
      for (int kb = 0; kb < 2; ++kb)
        acc[tj] = __builtin_amdgcn_mfma_f32_16x16x32_bf16(
            hf[ti][kb], hf[tj][kb], acc[tj], 0, 0, 0);

    // softmax over key index. C layout: row = 16*ti + 4*g + r, col = 16*tj + c16.
    float inv[4];
    #pragma unroll
    for (int r = 0; r < 4; ++r) {
      float mx = -1e30f;
      #pragma unroll
      for (int tj = 0; tj < 4; ++tj) {
        const float sv = (tj * 16 + c16 < L) ? acc[tj][r] : -1e30f;
        acc[tj][r] = sv;
        mx = fmaxf(mx, sv);
      }
      #pragma unroll
      for (int off = 1; off < 16; off <<= 1)
        mx = fmaxf(mx, __shfl_xor(mx, off, 64));
      float sum = 0.f;
      #pragma unroll
      for (int tj = 0; tj < 4; ++tj) {
        const float p = __expf(acc[tj][r] - mx);
        acc[tj][r] = p;
        sum += p;
      }
      #pragma unroll
      for (int off = 1; off < 16; off <<= 1)
        sum += __shfl_xor(sum, off, 64);
      inv[r] = 1.0f / sum;  // normalization deferred to epilogue
    }

    // P tile (bf16) into own 16 rows of Hs
    #pragma unroll
    for (int tj = 0; tj < 4; ++tj)
      #pragma unroll
      for (int r = 0; r < 4; ++r)
        P[(g * 4 + r) * STR + tj * 16 + c16] = f2bf(acc[tj][r]);

    LDSWAIT();  // order ds_write(P) -> ds_read(pf) within the wave

    bf16x8 pf[2];
    #pragma unroll
    for (int kb = 0; kb < 2; ++kb)
      pf[kb] = *(const bf16x8*)&P[c16 * STR + kb * 32 + g * 8];

    f32x4 o[4];
    #pragma unroll
    for (int tjd = 0; tjd < 4; ++tjd) {
      f32x4 z = {0.f, 0.f, 0.f, 0.f};
      o[tjd] = z;
    }
    #pragma unroll
    for (int tjd = 0; tjd < 4; ++tjd)
      #pragma unroll
      for (int kb = 0; kb < 2; ++kb)
        o[tjd] = __builtin_amdgcn_mfma_f32_16x16x32_bf16(
            pf[kb], vf[tjd][kb], o[tjd], 0, 0, 0);

    #pragma unroll
    for (int r = 0; r < 4; ++r) {
      const int row = ti * 16 + g * 4 + r;
      if (row < L) {
        float* dst = out + (size_t)(start + row) * D;
        const float sc = inv[r];
        #pragma unroll
        for (int tjd = 0; tjd < 4; ++tjd)
          dst[tjd * 16 + c16] = o[tjd][r] * sc;
      }
    }
  }
}

extern "C" void kernel_launch(void* const* d_in, const int* in_sizes, int n_in,
                              void* d_out, int out_size, void* d_ws, size_t ws_size,
                              hipStream_t stream) {
  const float* h = (const float*)d_in[0];
  const int* sse = (const int*)d_in[1];
  float* out = (float*)d_out;
  const int nseq = in_sizes[1] / 2;  // 4096
  seq_attn_kernel<<<nseq, 256, 0, stream>>>(h, sse, out);
}

// Round 9
// 76.865 us; speedup vs baseline: 1.2065x; 1.2065x over previous
//
#include <hip/hip_runtime.h>

#define D 64
#define STR 72  // LDS row stride in bf16 elems (r4-verbatim)

typedef __attribute__((ext_vector_type(8))) short bf16x8;
typedef __attribute__((ext_vector_type(4))) float f32x4;
typedef __attribute__((ext_vector_type(4))) unsigned int u32x4;

static __device__ __forceinline__ unsigned short f2bf(float f) {
  unsigned u = __builtin_bit_cast(unsigned, f);
  u += 0x7fffu + ((u >> 16) & 1u);  // RNE
  return (unsigned short)(u >> 16);
}

// r4's exact wave-private LDS ordering macro (P write -> pf read, own region)
#define LDSWAIT() asm volatile("s_waitcnt lgkmcnt(0)" ::: "memory")

// One BLOCK per sequence; 4 waves split the query tiles (wave w -> tile w).
// H staged ONCE into shared LDS (9.2 KB). r8 postmortem: __launch_bounds__
// (256,8) capped VGPR at 64 -> mass spill to scratch (VGPR=32, WRITE 250MB).
// ONLY change vs r8: bounds (256,4) -> cap 128 VGPR, no spills; VGPR~64 still
// yields 8 blocks/CU (512/64 = 8 waves/SIMD), LDS allows 17.
__global__ __launch_bounds__(256, 4)
void seq_attn_kernel(const float* __restrict__ h,
                     const int* __restrict__ sse,  // int32 (JAX x64 disabled)
                     float* __restrict__ out) {
  __shared__ unsigned short Hs[64 * STR];  // 9216 B: H tile, later reused for P

  const int tid = threadIdx.x;
  const int w = tid >> 6;
  const int lane = tid & 63;

  const int s = blockIdx.x;
  const int start = sse[2 * s];
  const int L = sse[2 * s + 1] - start;
  const int nt = (L + 15) >> 4;  // live 16-row tiles
  const int g = lane >> 4;
  const int c16 = lane & 15;

  const float* src = h + (size_t)start * D;

  // ---- stage H fp32->bf16 into shared Hs, 256 threads, zero-pad rows >= L ----
  // thread -> row = tid>>2, 64B chunk = (tid&3)*16; whole seq region contiguous.
  {
    const int r = tid >> 2;
    const int c0 = (tid & 3) * 16;
    const bool ok = (r < L);
    const float4 fz = make_float4(0.f, 0.f, 0.f, 0.f);
    const float* p0 = src + (size_t)r * D + c0;
    float4 v0 = ok ? *(const float4*)(p0 + 0) : fz;
    float4 v1 = ok ? *(const float4*)(p0 + 4) : fz;
    float4 v2 = ok ? *(const float4*)(p0 + 8) : fz;
    float4 v3 = ok ? *(const float4*)(p0 + 12) : fz;
    *(ushort4*)&Hs[r * STR + c0 + 0]  = make_ushort4(f2bf(v0.x), f2bf(v0.y), f2bf(v0.z), f2bf(v0.w));
    *(ushort4*)&Hs[r * STR + c0 + 4]  = make_ushort4(f2bf(v1.x), f2bf(v1.y), f2bf(v1.z), f2bf(v1.w));
    *(ushort4*)&Hs[r * STR + c0 + 8]  = make_ushort4(f2bf(v2.x), f2bf(v2.y), f2bf(v2.z), f2bf(v2.w));
    *(ushort4*)&Hs[r * STR + c0 + 12] = make_ushort4(f2bf(v3.x), f2bf(v3.y), f2bf(v3.z), f2bf(v3.w));
  }
  __syncthreads();

  // ---- fragment loads from shared Hs (r4-verbatim addressing; same for all waves) ----
  bf16x8 hf[4][2];
  #pragma unroll
  for (int t = 0; t < 4; ++t)
    #pragma unroll
    for (int kb = 0; kb < 2; ++kb)
      hf[t][kb] = *(const bf16x8*)&Hs[(t * 16 + c16) * STR + kb * 32 + g * 8];

  bf16x8 vf[4][2];
  #pragma unroll
  for (int t = 0; t < 4; ++t)
    #pragma unroll
    for (int kb = 0; kb < 2; ++kb) {
      u32x4 wv;
      #pragma unroll
      for (int dd = 0; dd < 4; ++dd) {
        const int k0 = kb * 32 + g * 8 + 2 * dd;
        const unsigned lo = Hs[k0 * STR + t * 16 + c16];
        const unsigned hi2 = Hs[(k0 + 1) * STR + t * 16 + c16];
        wv[dd] = lo | (hi2 << 16);
      }
      vf[t][kb] = __builtin_bit_cast(bf16x8, wv);
    }

  __syncthreads();  // all fragment reads done before P overwrites Hs

  // ---- wave w computes query tile w (r4 per-tile body verbatim, ti = w) ----
  const int ti = w;
  if (ti < nt) {
    unsigned short* P = Hs + ti * 16 * STR;  // wave-private 16-row region

    f32x4 acc[4];
    #pragma unroll
    for (int tj = 0; tj < 4; ++tj) {
      f32x4 z = {0.f, 0.f, 0.f, 0.f};
      acc[tj] = z;
    }
    #pragma unroll
    for (int tj = 0; tj < 4; ++tj)
      #pragma unroll
      for (int kb = 0; kb < 2; ++kb)
        acc[tj] = __builtin_amdgcn_mfma_f32_16x16x32_bf16(
            hf[ti][kb], hf[tj][kb], acc[tj], 0, 0, 0);

    // softmax over key index. C layout: row = 16*ti + 4*g + r, col = 16*tj + c16.
    float inv[4];
    #pragma unroll
    for (int r = 0; r < 4; ++r) {
      float mx = -1e30f;
      #pragma unroll
      for (int tj = 0; tj < 4; ++tj) {
        const float sv = (tj * 16 + c16 < L) ? acc[tj][r] : -1e30f;
        acc[tj][r] = sv;
        mx = fmaxf(mx, sv);
      }
      #pragma unroll
      for (int off = 1; off < 16; off <<= 1)
        mx = fmaxf(mx, __shfl_xor(mx, off, 64));
      float sum = 0.f;
      #pragma unroll
      for (int tj = 0; tj < 4; ++tj) {
        const float p = __expf(acc[tj][r] - mx);
        acc[tj][r] = p;
        sum += p;
      }
      #pragma unroll
      for (int off = 1; off < 16; off <<= 1)
        sum += __shfl_xor(sum, off, 64);
      inv[r] = 1.0f / sum;  // normalization deferred to epilogue
    }

    // P tile (bf16) into own 16 rows of Hs
    #pragma unroll
    for (int tj = 0; tj < 4; ++tj)
      #pragma unroll
      for (int r = 0; r < 4; ++r)
        P[(g * 4 + r) * STR + tj * 16 + c16] = f2bf(acc[tj][r]);

    LDSWAIT();  // order ds_write(P) -> ds_read(pf) within the wave

    bf16x8 pf[2];
    #pragma unroll
    for (int kb = 0; kb < 2; ++kb)
      pf[kb] = *(const bf16x8*)&P[c16 * STR + kb * 32 + g * 8];

    f32x4 o[4];
    #pragma unroll
    for (int tjd = 0; tjd < 4; ++tjd) {
      f32x4 z = {0.f, 0.f, 0.f, 0.f};
      o[tjd] = z;
    }
    #pragma unroll
    for (int tjd = 0; tjd < 4; ++tjd)
      #pragma unroll
      for (int kb = 0; kb < 2; ++kb)
        o[tjd] = __builtin_amdgcn_mfma_f32_16x16x32_bf16(
            pf[kb], vf[tjd][kb], o[tjd], 0, 0, 0);

    #pragma unroll
    for (int r = 0; r < 4; ++r) {
      const int row = ti * 16 + g * 4 + r;
      if (row < L) {
        float* dst = out + (size_t)(start + row) * D;
        const float sc = inv[r];
        #pragma unroll
        for (int tjd = 0; tjd < 4; ++tjd)
          dst[tjd * 16 + c16] = o[tjd][r] * sc;
      }
    }
  }
}

extern "C" void kernel_launch(void* const* d_in, const int* in_sizes, int n_in,
                              void* d_out, int out_size, void* d_ws, size_t ws_size,
                              hipStream_t stream) {
  const float* h = (const float*)d_in[0];
  const int* sse = (const int*)d_in[1];
  float* out = (float*)d_out;
  const int nseq = in_sizes[1] / 2;  // 4096
  seq_attn_kernel<<<nseq, 256, 0, stream>>>(h, sse, out);
}

// Round 11
// 26.000 us; speedup vs baseline: 3.5669x; 2.9563x over previous
//
#include <hip/hip_runtime.h>

#define D 64
#define STR 72    // LDS row stride in bf16 elems
#define WAVES 4   // independent waves per block, one sequence each

typedef __attribute__((ext_vector_type(8))) short bf16x8;
typedef __attribute__((ext_vector_type(4))) float f32x4;
typedef __attribute__((ext_vector_type(4))) unsigned int u32x4;

static __device__ __forceinline__ unsigned short f2bf(float f) {
  unsigned u = __builtin_bit_cast(unsigned, f);
  u += 0x7fffu + ((u >> 16) & 1u);  // RNE
  return (unsigned short)(u >> 16);
}

// r4's exact wave-private LDS ordering macro
#define LDSWAIT() asm volatile("s_waitcnt lgkmcnt(0)" ::: "memory")

// DPP lane exchange on the VALU pipe (replaces ds_bpermute shuffles).
// ENCODING (r10 bug was here): row_ror:N = 0x120 + N.
//   0xB1  = quad_perm [1,0,3,2] (xor1)
//   0x4E  = quad_perm [2,3,0,1] (xor2)
//   0x124 = row_ror:4   (r10 had 0x125 = ror:5 -> non-covering fold -> garbage)
//   0x128 = row_ror:8   (r10 had 0x129 = ror:9)
// After xor1+xor2 each quad holds its quad-reduction; ror4 merges adjacent
// quads, ror8 merges the pairs -> all 16 lanes hold the row reduction.
#define DPP_MOV(x, ctrl)                                                     \
  __builtin_bit_cast(float, __builtin_amdgcn_update_dpp(                     \
      0, __builtin_bit_cast(int, x), (ctrl), 0xf, 0xf, true))

// r4 structure: one sequence per wave, 4 independent waves per block
// (s = b + 1024w; 1024 % 8 == 0 -> all 4 waves share the same L).
// ONLY change vs r4: 16-lane softmax reductions via DPP (VALU) instead of
// __shfl_xor (ds_bpermute) — moves 128 ops/wave off the shared LDS pipe.
__global__ __launch_bounds__(256, 4)
void seq_attn_kernel(const float* __restrict__ h,
                     const int* __restrict__ sse,  // int32 (JAX x64 disabled)
                     float* __restrict__ out) {
  __shared__ unsigned short HsAll[WAVES * 64 * STR];  // 36.9 KB/block

  const int tid = threadIdx.x;
  const int w = tid >> 6;
  const int lane = tid & 63;
  unsigned short* Hs = HsAll + w * (64 * STR);  // wave-private slice

  const int s = blockIdx.x + gridDim.x * w;
  const int start = sse[2 * s];
  const int L = sse[2 * s + 1] - start;
  const int nt = (L + 15) >> 4;  // live 16-row tiles
  const int g = lane >> 4;
  const int c16 = lane & 15;

  // ---- stage H fp32->bf16: all loads issued up front (one latency) ----
  {
    const float* src = h + (size_t)start * D;
    const int c4 = c16 * 4;
    float4 va[8], vb[8];
    #pragma unroll
    for (int it = 0; it < 8; ++it) {
      const int r = it * 4 + g;
      const int rc = (r < L) ? r : 0;  // clamp: safe, masked at write
      va[it] = *(const float4*)(src + rc * D + c4);
    }
    const bool hi = (L > 32);  // wave-uniform: skip dead upper-half loads
    #pragma unroll
    for (int it = 0; it < 8; ++it) {
      const int r = 32 + it * 4 + g;
      const int rc = (r < L) ? r : 0;
      vb[it] = hi ? *(const float4*)(src + rc * D + c4) : make_float4(0.f, 0.f, 0.f, 0.f);
    }
    #pragma unroll
    for (int it = 0; it < 8; ++it) {
      const int r = it * 4 + g;
      const bool ok = (r < L);
      ushort4 wv;
      wv.x = ok ? f2bf(va[it].x) : (unsigned short)0;
      wv.y = ok ? f2bf(va[it].y) : (unsigned short)0;
      wv.z = ok ? f2bf(va[it].z) : (unsigned short)0;
      wv.w = ok ? f2bf(va[it].w) : (unsigned short)0;
      *(ushort4*)&Hs[r * STR + c4] = wv;  // rows >= L zeroed (pad keys -> 0)
    }
    #pragma unroll
    for (int it = 0; it < 8; ++it) {
      const int r = 32 + it * 4 + g;
      const bool ok = (r < L);
      ushort4 wv;
      wv.x = ok ? f2bf(vb[it].x) : (unsigned short)0;
      wv.y = ok ? f2bf(vb[it].y) : (unsigned short)0;
      wv.z = ok ? f2bf(vb[it].z) : (unsigned short)0;
      wv.w = ok ? f2bf(vb[it].w) : (unsigned short)0;
      *(ushort4*)&Hs[r * STR + c4] = wv;
    }
  }
  LDSWAIT();  // ds_writes drained before fragment reads (wave-private order)

  // ---- hf: A-layout fragments of H (both operands of S = H H^T) ----
  bf16x8 hf[4][2];
  #pragma unroll
  for (int t = 0; t < 4; ++t)
    #pragma unroll
    for (int kb = 0; kb < 2; ++kb)
      hf[t][kb] = *(const bf16x8*)&Hs[(t * 16 + c16) * STR + kb * 32 + g * 8];

  // ---- vf: B-layout fragments for PV, preloaded BEFORE P overwrites Hs ----
  bf16x8 vf[4][2];
  #pragma unroll
  for (int t = 0; t < 4; ++t)
    #pragma unroll
    for (int kb = 0; kb < 2; ++kb) {
      u32x4 wv;
      #pragma unroll
      for (int dd = 0; dd < 4; ++dd) {
        const int k0 = kb * 32 + g * 8 + 2 * dd;
        const unsigned lo = Hs[k0 * STR + t * 16 + c16];
        const unsigned hi2 = Hs[(k0 + 1) * STR + t * 16 + c16];
        wv[dd] = lo | (hi2 << 16);
      }
      vf[t][kb] = __builtin_bit_cast(bf16x8, wv);
    }

  // ---- per 16-row tile: QK^T -> softmax -> P restage -> PV -> store ----
  #pragma unroll
  for (int ti = 0; ti < 4; ++ti) {
    if (ti >= nt) continue;  // wave-uniform

    f32x4 acc[4];
    #pragma unroll
    for (int tj = 0; tj < 4; ++tj) {
      f32x4 z = {0.f, 0.f, 0.f, 0.f};
      acc[tj] = z;
    }
    #pragma unroll
    for (int tj = 0; tj < 4; ++tj)
      #pragma unroll
      for (int kb = 0; kb < 2; ++kb)
        acc[tj] = __builtin_amdgcn_mfma_f32_16x16x32_bf16(
            hf[ti][kb], hf[tj][kb], acc[tj], 0, 0, 0);

    // softmax over key index. C layout: row = 16*ti + 4*g + r, col = 16*tj + c16.
    // 16-lane reduction entirely on VALU via DPP (was 8 ds_bpermute per r).
    float inv[4];
    #pragma unroll
    for (int r = 0; r < 4; ++r) {
      float mx = -1e30f;
      #pragma unroll
      for (int tj = 0; tj < 4; ++tj) {
        const float sv = (tj * 16 + c16 < L) ? acc[tj][r] : -1e30f;
        acc[tj][r] = sv;
        mx = fmaxf(mx, sv);
      }
      mx = fmaxf(mx, DPP_MOV(mx, 0xB1));   // quad_perm xor1
      mx = fmaxf(mx, DPP_MOV(mx, 0x4E));   // quad_perm xor2
      mx = fmaxf(mx, DPP_MOV(mx, 0x124));  // row_ror:4
      mx = fmaxf(mx, DPP_MOV(mx, 0x128));  // row_ror:8
      float sum = 0.f;
      #pragma unroll
      for (int tj = 0; tj < 4; ++tj) {
        const float p = __expf(acc[tj][r] - mx);
        acc[tj][r] = p;
        sum += p;
      }
      sum += DPP_MOV(sum, 0xB1);
      sum += DPP_MOV(sum, 0x4E);
      sum += DPP_MOV(sum, 0x124);
      sum += DPP_MOV(sum, 0x128);
      inv[r] = 1.0f / sum;  // normalization deferred to epilogue
    }

    // P tile (bf16) into Hs rows [16*ti, 16*ti+16) — tile-disjoint, no WAR
    #pragma unroll
    for (int tj = 0; tj < 4; ++tj)
      #pragma unroll
      for (int r = 0; r < 4; ++r)
        Hs[(ti * 16 + g * 4 + r) * STR + tj * 16 + c16] = f2bf(acc[tj][r]);

    LDSWAIT();  // order ds_write(P) -> ds_read(pf) within the wave

    bf16x8 pf[2];
    #pragma unroll
    for (int kb = 0; kb < 2; ++kb)
      pf[kb] = *(const bf16x8*)&Hs[(ti * 16 + c16) * STR + kb * 32 + g * 8];

    f32x4 o[4];
    #pragma unroll
    for (int tjd = 0; tjd < 4; ++tjd) {
      f32x4 z = {0.f, 0.f, 0.f, 0.f};
      o[tjd] = z;
    }
    #pragma unroll
    for (int tjd = 0; tjd < 4; ++tjd)
      #pragma unroll
      for (int kb = 0; kb < 2; ++kb)
        o[tjd] = __builtin_amdgcn_mfma_f32_16x16x32_bf16(
            pf[kb], vf[tjd][kb], o[tjd], 0, 0, 0);

    #pragma unroll
    for (int r = 0; r < 4; ++r) {
      const int row = ti * 16 + g * 4 + r;
      if (row < L) {
        float* dst = out + (size_t)(start + row) * D;
        const float sc = inv[r];
        #pragma unroll
        for (int tjd = 0; tjd < 4; ++tjd)
          dst[tjd * 16 + c16] = o[tjd][r] * sc;
      }
    }
  }
}

extern "C" void kernel_launch(void* const* d_in, const int* in_sizes, int n_in,
                              void* d_out, int out_size, void* d_ws, size_t ws_size,
                              hipStream_t stream) {
  const float* h = (const float*)d_in[0];
  const int* sse = (const int*)d_in[1];
  float* out = (float*)d_out;
  const int nseq = in_sizes[1] / 2;  // 4096
  const int nblk = nseq / WAVES;     // 1024
  seq_attn_kernel<<<nblk, 64 * WAVES, 0, stream>>>(h, sse, out);
}